// Round 9
// baseline (198.930 us; speedup 1.0000x reference)
//
#include <hip/hip_runtime.h>
#include <hip/hip_bf16.h>
#include <math.h>

#define BATCH 2
#define SEQ   2048
#define EMB   1024
#define NH    16
#define HD    64
#define K_DIM 1024
#define QSCALE 0.18033688011f   /* 0.125 * log2(e): folded into q projection */

typedef __hip_bfloat16 bf16;
typedef __attribute__((ext_vector_type(8))) short short8;
typedef __attribute__((ext_vector_type(4))) short short4v;
typedef __attribute__((ext_vector_type(4))) float f32x4;
typedef __attribute__((ext_vector_type(2))) unsigned int uint2v;

// gfx950 HW packed f32->bf16 (RTNE)
__device__ __forceinline__ unsigned cvt_pk_bf16(float a, float b) {
    unsigned r;
    asm("v_cvt_pk_bf16_f32 %0, %1, %2" : "=v"(r) : "v"(a), "v"(b));
    return r;
}
__device__ __forceinline__ void st_bf2(bf16* p0, bf16* p1, float a, float b) {
    unsigned pk = cvt_pk_bf16(a, b);
    *(short*)p0 = (short)(pk & 0xffff);
    *(short*)p1 = (short)(pk >> 16);
}

// async global->LDS, 16B per lane; LDS dest = wave-uniform base + lane*16
__device__ __forceinline__ void gld_lds16(const bf16* g, bf16* l) {
    __builtin_amdgcn_global_load_lds(
        (const __attribute__((address_space(1))) unsigned int*)g,
        (__attribute__((address_space(3))) unsigned int*)l, 16, 0, 0);
}

// ---------------------------------------------------------------------------
// Convert x and Wq|Wk|Wv|Wo to bf16 into contiguous dst [xb | wq wk wv wo].
// ---------------------------------------------------------------------------
__global__ __launch_bounds__(256)
void cvt_pack(const float* __restrict__ x,  const float* __restrict__ wq,
              const float* __restrict__ wk, const float* __restrict__ wv,
              const float* __restrict__ wo, short* __restrict__ dst)
{
    size_t gid = ((size_t)blockIdx.x * 256 + threadIdx.x) * 4;
    int seg = (int)(gid >> 20);
    const float* src; size_t off;
    if (seg < 4)       { src = x;  off = gid; }
    else if (seg == 4) { src = wq; off = gid - ((size_t)4 << 20); }
    else if (seg == 5) { src = wk; off = gid - ((size_t)5 << 20); }
    else if (seg == 6) { src = wv; off = gid - ((size_t)6 << 20); }
    else               { src = wo; off = gid - ((size_t)7 << 20); }
    f32x4 v = *(const f32x4*)(src + off);
    uint2v pk = { cvt_pk_bf16(v[0], v[1]), cvt_pk_bf16(v[2], v[3]) };
    *(uint2v*)(dst + gid) = pk;
}

// ---------------------------------------------------------------------------
// Fused QKV GEMM v3: BK 32->64 + T2 chunk-XOR swizzle.
// R8 accounting: qkv ~40.6us at MfmaUtil 18% / occ 15% -> barrier-bound.
// BK=64 halves barrier pairs (32->16) and doubles MFMA per pair (16->32/wave).
// Naive [128][64] frag reads would be a 16-way bank conflict (row stride
// 128B); fix = 16B-chunk XOR swizzle, slot = chunk ^ (row&7):
//   - gld_lds16 dest stays LINEAR (required, m104); the GLOBAL source column
//     is inverse-permuted per-lane (rule #21) -- permutation stays inside one
//     128B row, so coalescing is preserved;
//   - frag read applies the same XOR -> 8 distinct banks per 16-lane group
//     (2-way = free).
// Deterministic: any index error = hard absmax fail, not a race.
// Epilogue verbatim from the verified round-0 kernel (scatter stores are
// fire-and-forget; R7 proved retiling them costs more than it saves).
// LDS 32KB -> 5 blocks/CU cap (unchanged occupancy regime).
// ---------------------------------------------------------------------------
__global__ __launch_bounds__(256)
void gemm_qkv3(const bf16* __restrict__ xb, const bf16* __restrict__ wb,
               const float* __restrict__ bq, const float* __restrict__ bk_,
               const float* __restrict__ bv_, const int* __restrict__ mask,
               bf16* __restrict__ q, bf16* __restrict__ kt, bf16* __restrict__ vt)
{
    __shared__ __align__(16) bf16 As[128 * 64];
    __shared__ __align__(16) bf16 Bs[128 * 64];

    const int tid  = threadIdx.x;
    const int proj = blockIdx.x >> 3;
    const int n0   = (blockIdx.x & 7) * 128;
    const int m0   = blockIdx.y * 128;
    const bf16* W  = wb + ((size_t)proj << 20);
    const float* bias = (proj == 0) ? bq : (proj == 1) ? bk_ : bv_;

    const int wave = tid >> 6, lane = tid & 63;
    const int wm = wave >> 1, wn = wave & 1;
    const int lr = lane & 15, lg = lane >> 4;
    const int srow = lane >> 3;                         // 8 lanes per 64-elem row
    const int scol = ((lane & 7) ^ (srow & 7)) * 8;     // inverse-swizzled source chunk

    f32x4 acc[4][4];
    for (int mi = 0; mi < 4; ++mi)
        for (int ni = 0; ni < 4; ++ni) acc[mi][ni] = (f32x4){0.f,0.f,0.f,0.f};

    for (int k0 = 0; k0 < K_DIM; k0 += 64) {
        for (int i = 0; i < 4; ++i) {
            int rb = wave * 32 + i * 8;                 // rb % 8 == 0
            gld_lds16(&xb[(size_t)(m0 + rb + srow) * K_DIM + k0 + scol], &As[rb * 64]);
            gld_lds16(&W [(size_t)(n0 + rb + srow) * K_DIM + k0 + scol], &Bs[rb * 64]);
        }
        __syncthreads();
        #pragma unroll
        for (int kh = 0; kh < 2; ++kh) {
            short8 af[4], bf_[4];
            for (int mi = 0; mi < 4; ++mi) {
                int R = wm * 64 + mi * 16 + lr;         // R&7 == lr&7
                af[mi] = *(const short8*)&As[R * 64 + (((kh * 4 + lg) ^ (lr & 7)) * 8)];
            }
            for (int ni = 0; ni < 4; ++ni) {
                int R = wn * 64 + ni * 16 + lr;
                bf_[ni] = *(const short8*)&Bs[R * 64 + (((kh * 4 + lg) ^ (lr & 7)) * 8)];
            }
            for (int mi = 0; mi < 4; ++mi)
                for (int ni = 0; ni < 4; ++ni)
                    acc[mi][ni] = __builtin_amdgcn_mfma_f32_16x16x32_bf16(
                        af[mi], bf_[ni], acc[mi][ni], 0, 0, 0);
        }
        __syncthreads();
    }

    int msk[4][4];
    if (proj != 0) {
        for (int mi = 0; mi < 4; ++mi) {
            int mbase = m0 + wm * 64 + mi * 16 + lg * 4;
            int b = mbase >> 11, s0 = mbase & 2047;
            int4 mm = *(const int4*)&mask[(size_t)b * SEQ + s0];
            msk[mi][0] = mm.x; msk[mi][1] = mm.y; msk[mi][2] = mm.z; msk[mi][3] = mm.w;
        }
    }

    for (int mi = 0; mi < 4; ++mi)
        for (int ni = 0; ni < 4; ++ni) {
            int n = n0 + wn * 64 + ni * 16 + lr;
            float bvv = bias[n];
            int h = n >> 6, d = n & 63;
            int mbase = m0 + wm * 64 + mi * 16 + lg * 4;
            int b = mbase >> 11, s0 = mbase & 2047;
            float v0 = acc[mi][ni][0] + bvv, v1 = acc[mi][ni][1] + bvv;
            float v2 = acc[mi][ni][2] + bvv, v3 = acc[mi][ni][3] + bvv;
            if (proj == 0) {
                bf16* p = q + ((((size_t)b * NH) + h) * SEQ + s0) * HD + d;
                st_bf2(p,          p + HD,     v0 * QSCALE, v1 * QSCALE);
                st_bf2(p + 2 * HD, p + 3 * HD, v2 * QSCALE, v3 * QSCALE);
            } else if (proj == 1) {
                if (msk[mi][0]) v0 = 0.f;
                if (msk[mi][1]) v1 = 0.f;
                if (msk[mi][2]) v2 = 0.f;
                if (msk[mi][3]) v3 = 0.f;
                bf16* p = kt + ((((size_t)b * NH) + h) * SEQ + s0) * HD + d;
                st_bf2(p,          p + HD,     v0, v1);
                st_bf2(p + 2 * HD, p + 3 * HD, v2, v3);
            } else {
                if (msk[mi][0]) v0 = 0.f;
                if (msk[mi][1]) v1 = 0.f;
                if (msk[mi][2]) v2 = 0.f;
                if (msk[mi][3]) v3 = 0.f;
                uint2v pk = { cvt_pk_bf16(v0, v1), cvt_pk_bf16(v2, v3) };
                *(uint2v*)((short*)vt + ((((size_t)b * NH) + h) * HD + d) * SEQ + s0) = pk;
            }
        }
}

// ---------------------------------------------------------------------------
// Out projection v4: same BK=64 + swizzle transform. R8 proved the 128x128
// 8-wave retile alone was NULL (~50us): per-wave MFMA per barrier-pair stayed
// 8. BK=64 doubles it to 16 and halves barrier pairs (32->16).
// Epilogue verbatim from out3 (verified green in R8).
// ---------------------------------------------------------------------------
__global__ __launch_bounds__(512)
void gemm_out4(const bf16* __restrict__ A, const bf16* __restrict__ W,
               const float* __restrict__ bias, float* __restrict__ C)
{
    __shared__ __align__(16) bf16 As[128 * 64];
    __shared__ __align__(16) bf16 Bs[128 * 64];

    const int tid = threadIdx.x;
    const int n0  = blockIdx.x * 128;
    const int m0  = blockIdx.y * 128;
    const int wave = tid >> 6, lane = tid & 63;
    const int wm = wave >> 2, wn = wave & 3;
    const int lr = lane & 15, lg = lane >> 4;
    const int srow = lane >> 3;
    const int scol = ((lane & 7) ^ (srow & 7)) * 8;

    f32x4 acc[4][2];
    for (int mi = 0; mi < 4; ++mi)
        for (int ni = 0; ni < 2; ++ni) acc[mi][ni] = (f32x4){0.f,0.f,0.f,0.f};

    for (int k0 = 0; k0 < K_DIM; k0 += 64) {
        for (int i = 0; i < 2; ++i) {
            int rb = wave * 16 + i * 8;                 // 8 waves x 16 rows = 128
            gld_lds16(&A[(size_t)(m0 + rb + srow) * K_DIM + k0 + scol], &As[rb * 64]);
            gld_lds16(&W[(size_t)(n0 + rb + srow) * K_DIM + k0 + scol], &Bs[rb * 64]);
        }
        __syncthreads();
        #pragma unroll
        for (int kh = 0; kh < 2; ++kh) {
            short8 af[4], bf_[2];
            for (int mi = 0; mi < 4; ++mi) {
                int R = wm * 64 + mi * 16 + lr;
                af[mi] = *(const short8*)&As[R * 64 + (((kh * 4 + lg) ^ (lr & 7)) * 8)];
            }
            for (int ni = 0; ni < 2; ++ni) {
                int R = wn * 32 + ni * 16 + lr;
                bf_[ni] = *(const short8*)&Bs[R * 64 + (((kh * 4 + lg) ^ (lr & 7)) * 8)];
            }
            for (int mi = 0; mi < 4; ++mi)
                for (int ni = 0; ni < 2; ++ni)
                    acc[mi][ni] = __builtin_amdgcn_mfma_f32_16x16x32_bf16(
                        af[mi], bf_[ni], acc[mi][ni], 0, 0, 0);
        }
        __syncthreads();
    }

    for (int mi = 0; mi < 4; ++mi)
        for (int ni = 0; ni < 2; ++ni) {
            int n = n0 + wn * 32 + ni * 16 + lr;
            float bvv = bias[n];
            int mbase = m0 + wm * 64 + mi * 16 + lg * 4;
            for (int r = 0; r < 4; ++r)
                C[(size_t)(mbase + r) * EMB + n] = acc[mi][ni][r] + bvv;
        }
}

// ---------------------------------------------------------------------------
// Flash attention v11 (verified green, ~50us): round-0 attn_flash6 + XCD
// swizzle. Counters (R6): FETCH 69.7->12.4MB (K/V L2-resident) but dur
// unchanged -> attn is structure-bound, not memory-bound. In-loop edits
// (v7/v8/v10) all corrupt; kernel FROZEN in this form.
// ---------------------------------------------------------------------------
__global__ __launch_bounds__(512, 4)
void attn_flash11(const bf16* __restrict__ q, const bf16* __restrict__ k,
                  const bf16* __restrict__ vt, const int* __restrict__ mask,
                  bf16* __restrict__ attn)
{
    __shared__ __align__(16) char smem[73728];
    bf16* PbB = (bf16*)smem;              // [2][128][72]  (g0 doubles as Q stage)
    bf16* KsB = (bf16*)(smem + 36864);    // [2][64][72]
    bf16* VtB = (bf16*)(smem + 55296);    // [2][64][72]
    __shared__ float sred[8];

    // XCD-aware bijective relabeling of (q0, h, b); grid = dim3(16,16,2).
    const int bid = (int)blockIdx.x + ((int)blockIdx.y << 4) + ((int)blockIdx.z << 8);
    const int swz = (bid & 7) * 64 + (bid >> 3);
    const int q0  = (swz & 15) * 128;
    const int h   = (swz >> 4) & 15;
    const int b   = swz >> 8;

    const int tid  = threadIdx.x;
    const int lane = tid & 63;
    const int wave = tid >> 6;            // 0..7
    const int g    = wave >> 2;           // key group 0/1
    const int qoff = (wave & 3) * 32;     // this wave's 32 query rows
    const int lr   = lane & 15;
    const int lg   = lane >> 4;

    const size_t bh  = ((size_t)b * NH + h) * SEQ;
    const size_t bhd = ((size_t)b * NH + h) * HD;

    // masked-key count for batch b
    int4 mm = *(const int4*)&mask[(size_t)b * SEQ + tid * 4];
    int cnt = (mm.x != 0) + (mm.y != 0) + (mm.z != 0) + (mm.w != 0);
    for (int off = 32; off; off >>= 1) cnt += __shfl_xor(cnt, off);
    if (lane == 0) sred[wave] = (float)cnt;

    // stage Q tile into Pb[0] region (8192 elems, 16/thread)
    for (int i = 0; i < 2; ++i) {
        int e = tid + i * 512;
        int r = e >> 3, c = (e & 7) * 8;
        *(short8*)&PbB[r * 72 + c] = *(const short8*)&q[(bh + q0 + r) * HD + c];
    }
    __syncthreads();

    const float nmask = sred[0] + sred[1] + sred[2] + sred[3] +
                        sred[4] + sred[5] + sred[6] + sred[7];

    // Q as B-operand frags for this wave's 32 queries (2 x 16)
    short8 bq_[2][2];
    for (int mi = 0; mi < 2; ++mi) {
        bq_[mi][0] = *(const short8*)&PbB[(qoff + mi * 16 + lr) * 72 + lg * 8];
        bq_[mi][1] = *(const short8*)&PbB[(qoff + mi * 16 + lr) * 72 + 32 + lg * 8];
    }

    short8 ones;
    for (int j = 0; j < 8; ++j) ones[j] = (short)0x3F80;   // bf16 1.0

    f32x4 o[2][4], lacc[2];
    for (int mi = 0; mi < 2; ++mi) {
        lacc[mi] = (f32x4){0.f,0.f,0.f,0.f};
        for (int db = 0; db < 4; ++db) o[mi][db] = (f32x4){0.f,0.f,0.f,0.f};
    }

    // staging: 512 threads x 2 chunks cover both groups' K and V tiles
    short8 pk_[2], pv_[2];
    auto ld = [&](int it) {
        int k0 = it * 64;
        for (int i = 0; i < 2; ++i) {
            int e = tid + i * 512;
            int gg = e >> 9, r = (e >> 3) & 63, c = (e & 7) * 8;
            int kk = k0 + gg * 1024;
            pk_[i] = *(const short8*)&k [(bh + kk + r) * HD + c];
            pv_[i] = *(const short8*)&vt[(bhd + r) * SEQ + kk + c];
        }
    };
    ld(0);

    for (int it = 0; it < 16; ++it) {
        for (int i = 0; i < 2; ++i) {
            int e = tid + i * 512;
            int gg = e >> 9, r = (e >> 3) & 63, c = (e & 7) * 8;
            *(short8*)&KsB[(gg * 64 + r) * 72 + c] = pk_[i];
            *(short8*)&VtB[(gg * 64 + r) * 72 + c] = pv_[i];
        }
        __syncthreads();
        if (it + 1 < 16) ld(it + 1);

        // S^T = K Q^T over this group's 64-key tile
        for (int cb = 0; cb < 4; ++cb) {
            short8 a0 = *(const short8*)&KsB[(g * 64 + cb * 16 + lr) * 72 + lg * 8];
            short8 a1 = *(const short8*)&KsB[(g * 64 + cb * 16 + lr) * 72 + 32 + lg * 8];
            for (int mi = 0; mi < 2; ++mi) {
                f32x4 cc = (f32x4){0.f,0.f,0.f,0.f};
                cc = __builtin_amdgcn_mfma_f32_16x16x32_bf16(a0, bq_[mi][0], cc, 0, 0, 0);
                cc = __builtin_amdgcn_mfma_f32_16x16x32_bf16(a1, bq_[mi][1], cc, 0, 0, 0);
                uint2v pkv = {
                    cvt_pk_bf16(__builtin_amdgcn_exp2f(cc[0]),
                                __builtin_amdgcn_exp2f(cc[1])),
                    cvt_pk_bf16(__builtin_amdgcn_exp2f(cc[2]),
                                __builtin_amdgcn_exp2f(cc[3])) };
                *(uint2v*)&PbB[(g * 128 + qoff + mi * 16 + lr) * 72 + cb * 16 + lg * 4] = pkv;
            }
        }

        // O += P V ; l += P 1   (wave-private P rows: no barrier needed)
        short8 ap[2][2];
        for (int mi = 0; mi < 2; ++mi) {
            ap[mi][0] = *(const short8*)&PbB[(g * 128 + qoff + mi * 16 + lr) * 72 + lg * 8];
            ap[mi][1] = *(const short8*)&PbB[(g * 128 + qoff + mi * 16 + lr) * 72 + 32 + lg * 8];
        }
        for (int db = 0; db < 4; ++db) {
            short8 bv0 = *(const short8*)&VtB[(g * 64 + db * 16 + lr) * 72 + lg * 8];
            short8 bv1 = *(const short8*)&VtB[(g * 64 + db * 16 + lr) * 72 + 32 + lg * 8];
            for (int mi = 0; mi < 2; ++mi) {
                o[mi][db] = __builtin_amdgcn_mfma_f32_16x16x32_bf16(ap[mi][0], bv0, o[mi][db], 0, 0, 0);
                o[mi][db] = __builtin_amdgcn_mfma_f32_16x16x32_bf16(ap[mi][1], bv1, o[mi][db], 0, 0, 0);
            }
        }
        for (int mi = 0; mi < 2; ++mi) {
            lacc[mi] = __builtin_amdgcn_mfma_f32_16x16x32_bf16(ap[mi][0], ones, lacc[mi], 0, 0, 0);
            lacc[mi] = __builtin_amdgcn_mfma_f32_16x16x32_bf16(ap[mi][1], ones, lacc[mi], 0, 0, 0);
        }
        __syncthreads();
    }

    // combine the two key-halves through LDS scratch, normalize, store
    float* Osc  = (float*)(smem + 36864);  // 32 KB over Ks+Vt
    float* larr = (float*)smem;            // over Pb[0]
    if (g == 1) {
        for (int mi = 0; mi < 2; ++mi) {
            for (int db = 0; db < 4; ++db)
                for (int r = 0; r < 4; ++r)
                    Osc[(qoff + mi * 16 + lg * 4 + r) * 64 + db * 16 + lr] = o[mi][db][r];
            if (lr == 0)
                for (int r = 0; r < 4; ++r)
                    larr[qoff + mi * 16 + lg * 4 + r] = lacc[mi][r];
        }
    }
    __syncthreads();
    if (g == 0) {
        for (int mi = 0; mi < 2; ++mi) {
            int qr = qoff + mi * 16 + lg * 4;
            f32x4 linv;
            for (int r = 0; r < 4; ++r)
                linv[r] = 1.f / (lacc[mi][r] + larr[qr + r] - nmask);
            for (int db = 0; db < 4; ++db) {
                int col = h * HD + db * 16 + lr;
                float vv[4];
                for (int r = 0; r < 4; ++r)
                    vv[r] = (o[mi][db][r] + Osc[(qr + r) * 64 + db * 16 + lr]) * linv[r];
                bf16* p = attn + ((size_t)b * SEQ + q0 + qr) * EMB + col;
                st_bf2(p,           p + EMB,     vv[0], vv[1]);
                st_bf2(p + 2 * EMB, p + 3 * EMB, vv[2], vv[3]);
            }
        }
    }
}

// ---------------------------------------------------------------------------
extern "C" void kernel_launch(void* const* d_in, const int* in_sizes, int n_in,
                              void* d_out, int out_size, void* d_ws, size_t ws_size,
                              hipStream_t stream)
{
    const float* x    = (const float*)d_in[0];
    const int*   mask = (const int*)d_in[1];
    const float* Wq   = (const float*)d_in[2];
    const float* bq   = (const float*)d_in[3];
    const float* Wk   = (const float*)d_in[4];
    const float* bk   = (const float*)d_in[5];
    const float* Wv   = (const float*)d_in[6];
    const float* bv   = (const float*)d_in[7];
    const float* Wo   = (const float*)d_in[8];
    const float* bo   = (const float*)d_in[9];
    float* out = (float*)d_out;

    const size_t TENS = (size_t)BATCH * SEQ * EMB;   // 2^22
    bf16* q    = (bf16*)d_ws;
    bf16* kt   = q    + TENS;
    bf16* vt   = kt   + TENS;
    bf16* attn = vt   + TENS;
    bf16* xb   = attn + TENS;
    bf16* wb   = xb   + TENS;     // 4 x 2^20 = TENS

    cvt_pack<<<8192, 256, 0, stream>>>(x, Wq, Wk, Wv, Wo, (short*)xb);

    gemm_qkv3<<<dim3(24, 32), 256, 0, stream>>>(xb, wb, bq, bk, bv, mask, q, kt, vt);

    attn_flash11<<<dim3(SEQ / 128, NH, BATCH), 512, 0, stream>>>(q, kt, vt, mask, attn);

    gemm_out4<<<dim3(EMB / 128, 32), 512, 0, stream>>>(attn, wb + ((size_t)3 << 20), bo, out);
}

// Round 10
// 191.775 us; speedup vs baseline: 1.0373x; 1.0373x over previous
//
#include <hip/hip_runtime.h>
#include <hip/hip_bf16.h>
#include <math.h>

#define BATCH 2
#define SEQ   2048
#define EMB   1024
#define NH    16
#define HD    64
#define K_DIM 1024
#define QSCALE 0.18033688011f   /* 0.125 * log2(e): folded into q projection */

typedef __hip_bfloat16 bf16;
typedef __attribute__((ext_vector_type(8))) short short8;
typedef __attribute__((ext_vector_type(4))) short short4v;
typedef __attribute__((ext_vector_type(4))) float f32x4;
typedef __attribute__((ext_vector_type(2))) unsigned int uint2v;

// gfx950 HW packed f32->bf16 (RTNE)
__device__ __forceinline__ unsigned cvt_pk_bf16(float a, float b) {
    unsigned r;
    asm("v_cvt_pk_bf16_f32 %0, %1, %2" : "=v"(r) : "v"(a), "v"(b));
    return r;
}
__device__ __forceinline__ void st_bf2(bf16* p0, bf16* p1, float a, float b) {
    unsigned pk = cvt_pk_bf16(a, b);
    *(short*)p0 = (short)(pk & 0xffff);
    *(short*)p1 = (short)(pk >> 16);
}

// async global->LDS, 16B per lane; LDS dest = wave-uniform base + lane*16
__device__ __forceinline__ void gld_lds16(const bf16* g, bf16* l) {
    __builtin_amdgcn_global_load_lds(
        (const __attribute__((address_space(1))) unsigned int*)g,
        (__attribute__((address_space(3))) unsigned int*)l, 16, 0, 0);
}

// ---------------------------------------------------------------------------
// Convert x and Wq|Wk|Wv|Wo to bf16 into contiguous dst [xb | wq wk wv wo].
// ---------------------------------------------------------------------------
__global__ __launch_bounds__(256)
void cvt_pack(const float* __restrict__ x,  const float* __restrict__ wq,
              const float* __restrict__ wk, const float* __restrict__ wv,
              const float* __restrict__ wo, short* __restrict__ dst)
{
    size_t gid = ((size_t)blockIdx.x * 256 + threadIdx.x) * 4;
    int seg = (int)(gid >> 20);
    const float* src; size_t off;
    if (seg < 4)       { src = x;  off = gid; }
    else if (seg == 4) { src = wq; off = gid - ((size_t)4 << 20); }
    else if (seg == 5) { src = wk; off = gid - ((size_t)5 << 20); }
    else if (seg == 6) { src = wv; off = gid - ((size_t)6 << 20); }
    else               { src = wo; off = gid - ((size_t)7 << 20); }
    f32x4 v = *(const f32x4*)(src + off);
    uint2v pk = { cvt_pk_bf16(v[0], v[1]), cvt_pk_bf16(v[2], v[3]) };
    *(uint2v*)(dst + gid) = pk;
}

// ---------------------------------------------------------------------------
// Fused QKV GEMM: round-0 verified body (BK=32; R9's BK=64+swizzle killed
// conflicts to 0 but regressed 40.6->57us -> conflicts/barrier-count were NOT
// the bottleneck). The exposed cost is the vmcnt(0) drain before each barrier:
// loads are issued right before the barrier with no compute cover, so drain
// time ~ load latency. FETCH=40MB says W panels miss L2 (re-fetched by every
// XCD). NEW (only change): XCD-aware bijective grid relabel -- all 32 m-blocks
// of each (proj, n-panel) land on one XCD, making W staging loads L2-hits
// (768 KB/XCD working set); A is served by the die-level L3. Same proven-safe
// change class as attn's swizzle (pure block-id permutation, no in-loop edit).
// ---------------------------------------------------------------------------
__global__ __launch_bounds__(256)
void gemm_qkv2(const bf16* __restrict__ xb, const bf16* __restrict__ wb,
               const float* __restrict__ bq, const float* __restrict__ bk_,
               const float* __restrict__ bv_, const int* __restrict__ mask,
               bf16* __restrict__ q, bf16* __restrict__ kt, bf16* __restrict__ vt)
{
    __shared__ __align__(16) bf16 As[128 * 32];
    __shared__ __align__(16) bf16 Bs[128 * 32];

    const int tid  = threadIdx.x;
    // 1-D grid of 768; swz = proj*256 + n*32 + m, XCD (bid&7) owns 96
    // consecutive swz => one XCD sees ~3 (proj,n) W-panels x all 32 m.
    const int bid  = (int)blockIdx.x;
    const int swz  = (bid & 7) * 96 + (bid >> 3);
    const int proj = swz >> 8;
    const int n0   = ((swz >> 5) & 7) * 128;
    const int m0   = (swz & 31) * 128;
    const bf16* W  = wb + ((size_t)proj << 20);
    const float* bias = (proj == 0) ? bq : (proj == 1) ? bk_ : bv_;

    const int wave = tid >> 6, lane = tid & 63;
    const int wm = wave >> 1, wn = wave & 1;
    const int lr = lane & 15, lg = lane >> 4;
    const int srow = lane >> 2;
    const int scol = (lane & 3) * 8;

    f32x4 acc[4][4];
    for (int mi = 0; mi < 4; ++mi)
        for (int ni = 0; ni < 4; ++ni) acc[mi][ni] = (f32x4){0.f,0.f,0.f,0.f};

    for (int k0 = 0; k0 < K_DIM; k0 += 32) {
        for (int i = 0; i < 2; ++i) {
            int rb = (wave * 2 + i) * 16;
            gld_lds16(&xb[(size_t)(m0 + rb + srow) * K_DIM + k0 + scol], &As[rb * 32]);
            gld_lds16(&W [(size_t)(n0 + rb + srow) * K_DIM + k0 + scol], &Bs[rb * 32]);
        }
        __syncthreads();
        short8 af[4], bf_[4];
        for (int mi = 0; mi < 4; ++mi)
            af[mi]  = *(const short8*)&As[(wm * 64 + mi * 16 + lr) * 32 + lg * 8];
        for (int ni = 0; ni < 4; ++ni)
            bf_[ni] = *(const short8*)&Bs[(wn * 64 + ni * 16 + lr) * 32 + lg * 8];
        for (int mi = 0; mi < 4; ++mi)
            for (int ni = 0; ni < 4; ++ni)
                acc[mi][ni] = __builtin_amdgcn_mfma_f32_16x16x32_bf16(
                    af[mi], bf_[ni], acc[mi][ni], 0, 0, 0);
        __syncthreads();
    }

    int msk[4][4];
    if (proj != 0) {
        for (int mi = 0; mi < 4; ++mi) {
            int mbase = m0 + wm * 64 + mi * 16 + lg * 4;
            int b = mbase >> 11, s0 = mbase & 2047;
            int4 mm = *(const int4*)&mask[(size_t)b * SEQ + s0];
            msk[mi][0] = mm.x; msk[mi][1] = mm.y; msk[mi][2] = mm.z; msk[mi][3] = mm.w;
        }
    }

    for (int mi = 0; mi < 4; ++mi)
        for (int ni = 0; ni < 4; ++ni) {
            int n = n0 + wn * 64 + ni * 16 + lr;
            float bvv = bias[n];
            int h = n >> 6, d = n & 63;
            int mbase = m0 + wm * 64 + mi * 16 + lg * 4;
            int b = mbase >> 11, s0 = mbase & 2047;
            float v0 = acc[mi][ni][0] + bvv, v1 = acc[mi][ni][1] + bvv;
            float v2 = acc[mi][ni][2] + bvv, v3 = acc[mi][ni][3] + bvv;
            if (proj == 0) {
                bf16* p = q + ((((size_t)b * NH) + h) * SEQ + s0) * HD + d;
                st_bf2(p,          p + HD,     v0 * QSCALE, v1 * QSCALE);
                st_bf2(p + 2 * HD, p + 3 * HD, v2 * QSCALE, v3 * QSCALE);
            } else if (proj == 1) {
                if (msk[mi][0]) v0 = 0.f;
                if (msk[mi][1]) v1 = 0.f;
                if (msk[mi][2]) v2 = 0.f;
                if (msk[mi][3]) v3 = 0.f;
                bf16* p = kt + ((((size_t)b * NH) + h) * SEQ + s0) * HD + d;
                st_bf2(p,          p + HD,     v0, v1);
                st_bf2(p + 2 * HD, p + 3 * HD, v2, v3);
            } else {
                if (msk[mi][0]) v0 = 0.f;
                if (msk[mi][1]) v1 = 0.f;
                if (msk[mi][2]) v2 = 0.f;
                if (msk[mi][3]) v3 = 0.f;
                uint2v pk = { cvt_pk_bf16(v0, v1), cvt_pk_bf16(v2, v3) };
                *(uint2v*)((short*)vt + ((((size_t)b * NH) + h) * HD + d) * SEQ + s0) = pk;
            }
        }
}

// ---------------------------------------------------------------------------
// Out projection v3 (R8-green form: 128x128, 8 waves, BK=32) + XCD-aware
// grid relabel: one n-panel (Wo 256 KB) per XCD -> W staging loads L2-hit.
// ---------------------------------------------------------------------------
__global__ __launch_bounds__(512)
void gemm_out3(const bf16* __restrict__ A, const bf16* __restrict__ W,
               const float* __restrict__ bias, float* __restrict__ C)
{
    __shared__ __align__(16) bf16 As[128 * 32];
    __shared__ __align__(16) bf16 Bs[128 * 32];

    const int tid = threadIdx.x;
    // 1-D grid of 256; swz = n*32 + m, XCD (bid&7) owns n-panel (bid&7).
    const int bid = (int)blockIdx.x;
    const int swz = (bid & 7) * 32 + (bid >> 3);
    const int n0  = (swz >> 5) * 128;
    const int m0  = (swz & 31) * 128;
    const int wave = tid >> 6, lane = tid & 63;
    const int wm = wave >> 2, wn = wave & 3;
    const int lr = lane & 15, lg = lane >> 4;
    const int srow = lane >> 2, scol = (lane & 3) * 8;

    f32x4 acc[4][2];
    for (int mi = 0; mi < 4; ++mi)
        for (int ni = 0; ni < 2; ++ni) acc[mi][ni] = (f32x4){0.f,0.f,0.f,0.f};

    for (int k0 = 0; k0 < K_DIM; k0 += 32) {
        {
            int rb = wave * 16;   // 8 waves x 16 rows cover all 128 rows
            gld_lds16(&A[(size_t)(m0 + rb + srow) * K_DIM + k0 + scol], &As[rb * 32]);
            gld_lds16(&W[(size_t)(n0 + rb + srow) * K_DIM + k0 + scol], &Bs[rb * 32]);
        }
        __syncthreads();
        short8 af[4], bf_[2];
        for (int mi = 0; mi < 4; ++mi)
            af[mi]  = *(const short8*)&As[(wm * 64 + mi * 16 + lr) * 32 + lg * 8];
        for (int ni = 0; ni < 2; ++ni)
            bf_[ni] = *(const short8*)&Bs[(wn * 32 + ni * 16 + lr) * 32 + lg * 8];
        for (int mi = 0; mi < 4; ++mi)
            for (int ni = 0; ni < 2; ++ni)
                acc[mi][ni] = __builtin_amdgcn_mfma_f32_16x16x32_bf16(
                    af[mi], bf_[ni], acc[mi][ni], 0, 0, 0);
        __syncthreads();
    }

    for (int mi = 0; mi < 4; ++mi)
        for (int ni = 0; ni < 2; ++ni) {
            int n = n0 + wn * 32 + ni * 16 + lr;
            float bvv = bias[n];
            int mbase = m0 + wm * 64 + mi * 16 + lg * 4;
            for (int r = 0; r < 4; ++r)
                C[(size_t)(mbase + r) * EMB + n] = acc[mi][ni][r] + bvv;
        }
}

// ---------------------------------------------------------------------------
// Flash attention v11 (verified green, ~50us): round-0 attn_flash6 + XCD
// swizzle. R6 counters: FETCH 69.7->12.4MB (K/V L2-resident), dur unchanged
// -> structure-bound. In-loop edits (v7/v8/v10) all corrupt; FROZEN.
// ---------------------------------------------------------------------------
__global__ __launch_bounds__(512, 4)
void attn_flash11(const bf16* __restrict__ q, const bf16* __restrict__ k,
                  const bf16* __restrict__ vt, const int* __restrict__ mask,
                  bf16* __restrict__ attn)
{
    __shared__ __align__(16) char smem[73728];
    bf16* PbB = (bf16*)smem;              // [2][128][72]  (g0 doubles as Q stage)
    bf16* KsB = (bf16*)(smem + 36864);    // [2][64][72]
    bf16* VtB = (bf16*)(smem + 55296);    // [2][64][72]
    __shared__ float sred[8];

    // XCD-aware bijective relabeling of (q0, h, b); grid = dim3(16,16,2).
    const int bid = (int)blockIdx.x + ((int)blockIdx.y << 4) + ((int)blockIdx.z << 8);
    const int swz = (bid & 7) * 64 + (bid >> 3);
    const int q0  = (swz & 15) * 128;
    const int h   = (swz >> 4) & 15;
    const int b   = swz >> 8;

    const int tid  = threadIdx.x;
    const int lane = tid & 63;
    const int wave = tid >> 6;            // 0..7
    const int g    = wave >> 2;           // key group 0/1
    const int qoff = (wave & 3) * 32;     // this wave's 32 query rows
    const int lr   = lane & 15;
    const int lg   = lane >> 4;

    const size_t bh  = ((size_t)b * NH + h) * SEQ;
    const size_t bhd = ((size_t)b * NH + h) * HD;

    // masked-key count for batch b
    int4 mm = *(const int4*)&mask[(size_t)b * SEQ + tid * 4];
    int cnt = (mm.x != 0) + (mm.y != 0) + (mm.z != 0) + (mm.w != 0);
    for (int off = 32; off; off >>= 1) cnt += __shfl_xor(cnt, off);
    if (lane == 0) sred[wave] = (float)cnt;

    // stage Q tile into Pb[0] region (8192 elems, 16/thread)
    for (int i = 0; i < 2; ++i) {
        int e = tid + i * 512;
        int r = e >> 3, c = (e & 7) * 8;
        *(short8*)&PbB[r * 72 + c] = *(const short8*)&q[(bh + q0 + r) * HD + c];
    }
    __syncthreads();

    const float nmask = sred[0] + sred[1] + sred[2] + sred[3] +
                        sred[4] + sred[5] + sred[6] + sred[7];

    // Q as B-operand frags for this wave's 32 queries (2 x 16)
    short8 bq_[2][2];
    for (int mi = 0; mi < 2; ++mi) {
        bq_[mi][0] = *(const short8*)&PbB[(qoff + mi * 16 + lr) * 72 + lg * 8];
        bq_[mi][1] = *(const short8*)&PbB[(qoff + mi * 16 + lr) * 72 + 32 + lg * 8];
    }

    short8 ones;
    for (int j = 0; j < 8; ++j) ones[j] = (short)0x3F80;   // bf16 1.0

    f32x4 o[2][4], lacc[2];
    for (int mi = 0; mi < 2; ++mi) {
        lacc[mi] = (f32x4){0.f,0.f,0.f,0.f};
        for (int db = 0; db < 4; ++db) o[mi][db] = (f32x4){0.f,0.f,0.f,0.f};
    }

    // staging: 512 threads x 2 chunks cover both groups' K and V tiles
    short8 pk_[2], pv_[2];
    auto ld = [&](int it) {
        int k0 = it * 64;
        for (int i = 0; i < 2; ++i) {
            int e = tid + i * 512;
            int gg = e >> 9, r = (e >> 3) & 63, c = (e & 7) * 8;
            int kk = k0 + gg * 1024;
            pk_[i] = *(const short8*)&k [(bh + kk + r) * HD + c];
            pv_[i] = *(const short8*)&vt[(bhd + r) * SEQ + kk + c];
        }
    };
    ld(0);

    for (int it = 0; it < 16; ++it) {
        for (int i = 0; i < 2; ++i) {
            int e = tid + i * 512;
            int gg = e >> 9, r = (e >> 3) & 63, c = (e & 7) * 8;
            *(short8*)&KsB[(gg * 64 + r) * 72 + c] = pk_[i];
            *(short8*)&VtB[(gg * 64 + r) * 72 + c] = pv_[i];
        }
        __syncthreads();
        if (it + 1 < 16) ld(it + 1);

        // S^T = K Q^T over this group's 64-key tile
        for (int cb = 0; cb < 4; ++cb) {
            short8 a0 = *(const short8*)&KsB[(g * 64 + cb * 16 + lr) * 72 + lg * 8];
            short8 a1 = *(const short8*)&KsB[(g * 64 + cb * 16 + lr) * 72 + 32 + lg * 8];
            for (int mi = 0; mi < 2; ++mi) {
                f32x4 cc = (f32x4){0.f,0.f,0.f,0.f};
                cc = __builtin_amdgcn_mfma_f32_16x16x32_bf16(a0, bq_[mi][0], cc, 0, 0, 0);
                cc = __builtin_amdgcn_mfma_f32_16x16x32_bf16(a1, bq_[mi][1], cc, 0, 0, 0);
                uint2v pkv = {
                    cvt_pk_bf16(__builtin_amdgcn_exp2f(cc[0]),
                                __builtin_amdgcn_exp2f(cc[1])),
                    cvt_pk_bf16(__builtin_amdgcn_exp2f(cc[2]),
                                __builtin_amdgcn_exp2f(cc[3])) };
                *(uint2v*)&PbB[(g * 128 + qoff + mi * 16 + lr) * 72 + cb * 16 + lg * 4] = pkv;
            }
        }

        // O += P V ; l += P 1   (wave-private P rows: no barrier needed)
        short8 ap[2][2];
        for (int mi = 0; mi < 2; ++mi) {
            ap[mi][0] = *(const short8*)&PbB[(g * 128 + qoff + mi * 16 + lr) * 72 + lg * 8];
            ap[mi][1] = *(const short8*)&PbB[(g * 128 + qoff + mi * 16 + lr) * 72 + 32 + lg * 8];
        }
        for (int db = 0; db < 4; ++db) {
            short8 bv0 = *(const short8*)&VtB[(g * 64 + db * 16 + lr) * 72 + lg * 8];
            short8 bv1 = *(const short8*)&VtB[(g * 64 + db * 16 + lr) * 72 + 32 + lg * 8];
            for (int mi = 0; mi < 2; ++mi) {
                o[mi][db] = __builtin_amdgcn_mfma_f32_16x16x32_bf16(ap[mi][0], bv0, o[mi][db], 0, 0, 0);
                o[mi][db] = __builtin_amdgcn_mfma_f32_16x16x32_bf16(ap[mi][1], bv1, o[mi][db], 0, 0, 0);
            }
        }
        for (int mi = 0; mi < 2; ++mi) {
            lacc[mi] = __builtin_amdgcn_mfma_f32_16x16x32_bf16(ap[mi][0], ones, lacc[mi], 0, 0, 0);
            lacc[mi] = __builtin_amdgcn_mfma_f32_16x16x32_bf16(ap[mi][1], ones, lacc[mi], 0, 0, 0);
        }
        __syncthreads();
    }

    // combine the two key-halves through LDS scratch, normalize, store
    float* Osc  = (float*)(smem + 36864);  // 32 KB over Ks+Vt
    float* larr = (float*)smem;            // over Pb[0]
    if (g == 1) {
        for (int mi = 0; mi < 2; ++mi) {
            for (int db = 0; db < 4; ++db)
                for (int r = 0; r < 4; ++r)
                    Osc[(qoff + mi * 16 + lg * 4 + r) * 64 + db * 16 + lr] = o[mi][db][r];
            if (lr == 0)
                for (int r = 0; r < 4; ++r)
                    larr[qoff + mi * 16 + lg * 4 + r] = lacc[mi][r];
        }
    }
    __syncthreads();
    if (g == 0) {
        for (int mi = 0; mi < 2; ++mi) {
            int qr = qoff + mi * 16 + lg * 4;
            f32x4 linv;
            for (int r = 0; r < 4; ++r)
                linv[r] = 1.f / (lacc[mi][r] + larr[qr + r] - nmask);
            for (int db = 0; db < 4; ++db) {
                int col = h * HD + db * 16 + lr;
                float vv[4];
                for (int r = 0; r < 4; ++r)
                    vv[r] = (o[mi][db][r] + Osc[(qr + r) * 64 + db * 16 + lr]) * linv[r];
                bf16* p = attn + ((size_t)b * SEQ + q0 + qr) * EMB + col;
                st_bf2(p,           p + EMB,     vv[0], vv[1]);
                st_bf2(p + 2 * EMB, p + 3 * EMB, vv[2], vv[3]);
            }
        }
    }
}

// ---------------------------------------------------------------------------
extern "C" void kernel_launch(void* const* d_in, const int* in_sizes, int n_in,
                              void* d_out, int out_size, void* d_ws, size_t ws_size,
                              hipStream_t stream)
{
    const float* x    = (const float*)d_in[0];
    const int*   mask = (const int*)d_in[1];
    const float* Wq   = (const float*)d_in[2];
    const float* bq   = (const float*)d_in[3];
    const float* Wk   = (const float*)d_in[4];
    const float* bk   = (const float*)d_in[5];
    const float* Wv   = (const float*)d_in[6];
    const float* bv   = (const float*)d_in[7];
    const float* Wo   = (const float*)d_in[8];
    const float* bo   = (const float*)d_in[9];
    float* out = (float*)d_out;

    const size_t TENS = (size_t)BATCH * SEQ * EMB;   // 2^22
    bf16* q    = (bf16*)d_ws;
    bf16* kt   = q    + TENS;
    bf16* vt   = kt   + TENS;
    bf16* attn = vt   + TENS;
    bf16* xb   = attn + TENS;
    bf16* wb   = xb   + TENS;     // 4 x 2^20 = TENS

    cvt_pack<<<8192, 256, 0, stream>>>(x, Wq, Wk, Wv, Wo, (short*)xb);

    gemm_qkv2<<<768, 256, 0, stream>>>(xb, wb, bq, bk, bv, mask, q, kt, vt);

    attn_flash11<<<dim3(SEQ / 128, NH, BATCH), 512, 0, stream>>>(q, kt, vt, mask, attn);

    gemm_out3<<<256, 512, 0, stream>>>(attn, wb + ((size_t)3 << 20), bo, out);
}

// Round 11
// 191.740 us; speedup vs baseline: 1.0375x; 1.0002x over previous
//
#include <hip/hip_runtime.h>
#include <hip/hip_bf16.h>
#include <math.h>

#define BATCH 2
#define SEQ   2048
#define EMB   1024
#define NH    16
#define HD    64
#define K_DIM 1024
#define QSCALE 0.18033688011f   /* 0.125 * log2(e): folded into q projection */

typedef __hip_bfloat16 bf16;
typedef __attribute__((ext_vector_type(8))) short short8;
typedef __attribute__((ext_vector_type(4))) short short4v;
typedef __attribute__((ext_vector_type(4))) float f32x4;
typedef __attribute__((ext_vector_type(2))) unsigned int uint2v;

// gfx950 HW packed f32->bf16 (RTNE)
__device__ __forceinline__ unsigned cvt_pk_bf16(float a, float b) {
    unsigned r;
    asm("v_cvt_pk_bf16_f32 %0, %1, %2" : "=v"(r) : "v"(a), "v"(b));
    return r;
}
__device__ __forceinline__ void st_bf2(bf16* p0, bf16* p1, float a, float b) {
    unsigned pk = cvt_pk_bf16(a, b);
    *(short*)p0 = (short)(pk & 0xffff);
    *(short*)p1 = (short)(pk >> 16);
}

// async global->LDS, 16B per lane; LDS dest = wave-uniform base + lane*16
__device__ __forceinline__ void gld_lds16(const bf16* g, bf16* l) {
    __builtin_amdgcn_global_load_lds(
        (const __attribute__((address_space(1))) unsigned int*)g,
        (__attribute__((address_space(3))) unsigned int*)l, 16, 0, 0);
}

// ---------------------------------------------------------------------------
// Convert x and Wq|Wk|Wv|Wo to bf16 into contiguous dst [xb | wq wk wv wo].
// ---------------------------------------------------------------------------
__global__ __launch_bounds__(256)
void cvt_pack(const float* __restrict__ x,  const float* __restrict__ wq,
              const float* __restrict__ wk, const float* __restrict__ wv,
              const float* __restrict__ wo, short* __restrict__ dst)
{
    size_t gid = ((size_t)blockIdx.x * 256 + threadIdx.x) * 4;
    int seg = (int)(gid >> 20);
    const float* src; size_t off;
    if (seg < 4)       { src = x;  off = gid; }
    else if (seg == 4) { src = wq; off = gid - ((size_t)4 << 20); }
    else if (seg == 5) { src = wk; off = gid - ((size_t)5 << 20); }
    else if (seg == 6) { src = wv; off = gid - ((size_t)6 << 20); }
    else               { src = wo; off = gid - ((size_t)7 << 20); }
    f32x4 v = *(const f32x4*)(src + off);
    uint2v pk = { cvt_pk_bf16(v[0], v[1]), cvt_pk_bf16(v[2], v[3]) };
    *(uint2v*)(dst + gid) = pk;
}

// ---------------------------------------------------------------------------
// Fused QKV GEMM (R10-green form: round-0 body + XCD grid relabel).
// ---------------------------------------------------------------------------
__global__ __launch_bounds__(256)
void gemm_qkv2(const bf16* __restrict__ xb, const bf16* __restrict__ wb,
               const float* __restrict__ bq, const float* __restrict__ bk_,
               const float* __restrict__ bv_, const int* __restrict__ mask,
               bf16* __restrict__ q, bf16* __restrict__ kt, bf16* __restrict__ vt)
{
    __shared__ __align__(16) bf16 As[128 * 32];
    __shared__ __align__(16) bf16 Bs[128 * 32];

    const int tid  = threadIdx.x;
    const int bid  = (int)blockIdx.x;
    const int swz  = (bid & 7) * 96 + (bid >> 3);
    const int proj = swz >> 8;
    const int n0   = ((swz >> 5) & 7) * 128;
    const int m0   = (swz & 31) * 128;
    const bf16* W  = wb + ((size_t)proj << 20);
    const float* bias = (proj == 0) ? bq : (proj == 1) ? bk_ : bv_;

    const int wave = tid >> 6, lane = tid & 63;
    const int wm = wave >> 1, wn = wave & 1;
    const int lr = lane & 15, lg = lane >> 4;
    const int srow = lane >> 2;
    const int scol = (lane & 3) * 8;

    f32x4 acc[4][4];
    for (int mi = 0; mi < 4; ++mi)
        for (int ni = 0; ni < 4; ++ni) acc[mi][ni] = (f32x4){0.f,0.f,0.f,0.f};

    for (int k0 = 0; k0 < K_DIM; k0 += 32) {
        for (int i = 0; i < 2; ++i) {
            int rb = (wave * 2 + i) * 16;
            gld_lds16(&xb[(size_t)(m0 + rb + srow) * K_DIM + k0 + scol], &As[rb * 32]);
            gld_lds16(&W [(size_t)(n0 + rb + srow) * K_DIM + k0 + scol], &Bs[rb * 32]);
        }
        __syncthreads();
        short8 af[4], bf_[4];
        for (int mi = 0; mi < 4; ++mi)
            af[mi]  = *(const short8*)&As[(wm * 64 + mi * 16 + lr) * 32 + lg * 8];
        for (int ni = 0; ni < 4; ++ni)
            bf_[ni] = *(const short8*)&Bs[(wn * 64 + ni * 16 + lr) * 32 + lg * 8];
        for (int mi = 0; mi < 4; ++mi)
            for (int ni = 0; ni < 4; ++ni)
                acc[mi][ni] = __builtin_amdgcn_mfma_f32_16x16x32_bf16(
                    af[mi], bf_[ni], acc[mi][ni], 0, 0, 0);
        __syncthreads();
    }

    int msk[4][4];
    if (proj != 0) {
        for (int mi = 0; mi < 4; ++mi) {
            int mbase = m0 + wm * 64 + mi * 16 + lg * 4;
            int b = mbase >> 11, s0 = mbase & 2047;
            int4 mm = *(const int4*)&mask[(size_t)b * SEQ + s0];
            msk[mi][0] = mm.x; msk[mi][1] = mm.y; msk[mi][2] = mm.z; msk[mi][3] = mm.w;
        }
    }

    for (int mi = 0; mi < 4; ++mi)
        for (int ni = 0; ni < 4; ++ni) {
            int n = n0 + wn * 64 + ni * 16 + lr;
            float bvv = bias[n];
            int h = n >> 6, d = n & 63;
            int mbase = m0 + wm * 64 + mi * 16 + lg * 4;
            int b = mbase >> 11, s0 = mbase & 2047;
            float v0 = acc[mi][ni][0] + bvv, v1 = acc[mi][ni][1] + bvv;
            float v2 = acc[mi][ni][2] + bvv, v3 = acc[mi][ni][3] + bvv;
            if (proj == 0) {
                bf16* p = q + ((((size_t)b * NH) + h) * SEQ + s0) * HD + d;
                st_bf2(p,          p + HD,     v0 * QSCALE, v1 * QSCALE);
                st_bf2(p + 2 * HD, p + 3 * HD, v2 * QSCALE, v3 * QSCALE);
            } else if (proj == 1) {
                if (msk[mi][0]) v0 = 0.f;
                if (msk[mi][1]) v1 = 0.f;
                if (msk[mi][2]) v2 = 0.f;
                if (msk[mi][3]) v3 = 0.f;
                bf16* p = kt + ((((size_t)b * NH) + h) * SEQ + s0) * HD + d;
                st_bf2(p,          p + HD,     v0, v1);
                st_bf2(p + 2 * HD, p + 3 * HD, v2, v3);
            } else {
                if (msk[mi][0]) v0 = 0.f;
                if (msk[mi][1]) v1 = 0.f;
                if (msk[mi][2]) v2 = 0.f;
                if (msk[mi][3]) v3 = 0.f;
                uint2v pk = { cvt_pk_bf16(v0, v1), cvt_pk_bf16(v2, v3) };
                *(uint2v*)((short*)vt + ((((size_t)b * NH) + h) * HD + d) * SEQ + s0) = pk;
            }
        }
}

// ---------------------------------------------------------------------------
// Out projection v5: 64x64 tiles, 128 thr / 2 waves, 1024 blocks.
// Cross-round analysis: every GEMM config with 1-2 blocks/CU lands ~45-50us
// (out2 512blk/2CU, out3 256blk/1CU both ~null); qkv with 3 blocks/CU runs
// ~3.7x the FLOP rate. The un-isolated structural variable is INDEPENDENT
// BLOCKS PER CU: separate blocks have separate barrier domains, so one
// block's MFMA covers another's staging drain (the mechanism that makes
// attn's 2-block/CU work). 1024 blocks = 4 blocks/CU (16 waves/CU).
// XCD swizzle: each XCD owns 2 n-panels -> its Wo slice (256 KB) L2-resident.
// Per-wave: acc[2][4] (32m x 64n), 8 MFMA/K-step; staging = qkv2's verified
// pattern specialized to 2 waves; epilogue = out3's verified store formula.
// Deterministic: index bug = hard absmax fail.
// ---------------------------------------------------------------------------
__global__ __launch_bounds__(128)
void gemm_out5(const bf16* __restrict__ A, const bf16* __restrict__ W,
               const float* __restrict__ bias, float* __restrict__ C)
{
    __shared__ __align__(16) bf16 As[64 * 32];
    __shared__ __align__(16) bf16 Bs[64 * 32];

    const int tid = threadIdx.x;
    // 1024 blocks; swz = n_tile*64 + m_tile; XCD (bid&7) owns 128 consecutive
    // swz = 2 n-panels x all 64 m-tiles.
    const int bid = (int)blockIdx.x;
    const int swz = (bid & 7) * 128 + (bid >> 3);
    const int n0  = (swz >> 6) * 64;      // 16 n-tiles
    const int m0  = (swz & 63) * 64;      // 64 m-tiles
    const int wave = tid >> 6, lane = tid & 63;   // wave 0/1
    const int lr = lane & 15, lg = lane >> 4;
    const int srow = lane >> 2, scol = (lane & 3) * 8;

    f32x4 acc[2][4];
    for (int mi = 0; mi < 2; ++mi)
        for (int ni = 0; ni < 4; ++ni) acc[mi][ni] = (f32x4){0.f,0.f,0.f,0.f};

    for (int k0 = 0; k0 < K_DIM; k0 += 32) {
        for (int i = 0; i < 2; ++i) {
            int rb = (wave * 2 + i) * 16;     // 2 waves x 2 issues x 16 = 64 rows
            gld_lds16(&A[(size_t)(m0 + rb + srow) * K_DIM + k0 + scol], &As[rb * 32]);
            gld_lds16(&W[(size_t)(n0 + rb + srow) * K_DIM + k0 + scol], &Bs[rb * 32]);
        }
        __syncthreads();
        short8 af[2], bf_[4];
        for (int mi = 0; mi < 2; ++mi)
            af[mi]  = *(const short8*)&As[(wave * 32 + mi * 16 + lr) * 32 + lg * 8];
        for (int ni = 0; ni < 4; ++ni)
            bf_[ni] = *(const short8*)&Bs[(ni * 16 + lr) * 32 + lg * 8];
        for (int mi = 0; mi < 2; ++mi)
            for (int ni = 0; ni < 4; ++ni)
                acc[mi][ni] = __builtin_amdgcn_mfma_f32_16x16x32_bf16(
                    af[mi], bf_[ni], acc[mi][ni], 0, 0, 0);
        __syncthreads();
    }

    for (int mi = 0; mi < 2; ++mi)
        for (int ni = 0; ni < 4; ++ni) {
            int n = n0 + ni * 16 + lr;
            float bvv = bias[n];
            int mbase = m0 + wave * 32 + mi * 16 + lg * 4;
            for (int r = 0; r < 4; ++r)
                C[(size_t)(mbase + r) * EMB + n] = acc[mi][ni][r] + bvv;
        }
}

// ---------------------------------------------------------------------------
// Flash attention v11 (verified green, ~49us): round-0 attn_flash6 + XCD
// swizzle. R6 counters: FETCH 69.7->12.4MB (K/V L2-resident), dur unchanged
// -> structure-bound. In-loop edits (v7/v8/v10) all corrupt; FROZEN.
// ---------------------------------------------------------------------------
__global__ __launch_bounds__(512, 4)
void attn_flash11(const bf16* __restrict__ q, const bf16* __restrict__ k,
                  const bf16* __restrict__ vt, const int* __restrict__ mask,
                  bf16* __restrict__ attn)
{
    __shared__ __align__(16) char smem[73728];
    bf16* PbB = (bf16*)smem;              // [2][128][72]  (g0 doubles as Q stage)
    bf16* KsB = (bf16*)(smem + 36864);    // [2][64][72]
    bf16* VtB = (bf16*)(smem + 55296);    // [2][64][72]
    __shared__ float sred[8];

    // XCD-aware bijective relabeling of (q0, h, b); grid = dim3(16,16,2).
    const int bid = (int)blockIdx.x + ((int)blockIdx.y << 4) + ((int)blockIdx.z << 8);
    const int swz = (bid & 7) * 64 + (bid >> 3);
    const int q0  = (swz & 15) * 128;
    const int h   = (swz >> 4) & 15;
    const int b   = swz >> 8;

    const int tid  = threadIdx.x;
    const int lane = tid & 63;
    const int wave = tid >> 6;            // 0..7
    const int g    = wave >> 2;           // key group 0/1
    const int qoff = (wave & 3) * 32;     // this wave's 32 query rows
    const int lr   = lane & 15;
    const int lg   = lane >> 4;

    const size_t bh  = ((size_t)b * NH + h) * SEQ;
    const size_t bhd = ((size_t)b * NH + h) * HD;

    // masked-key count for batch b
    int4 mm = *(const int4*)&mask[(size_t)b * SEQ + tid * 4];
    int cnt = (mm.x != 0) + (mm.y != 0) + (mm.z != 0) + (mm.w != 0);
    for (int off = 32; off; off >>= 1) cnt += __shfl_xor(cnt, off);
    if (lane == 0) sred[wave] = (float)cnt;

    // stage Q tile into Pb[0] region (8192 elems, 16/thread)
    for (int i = 0; i < 2; ++i) {
        int e = tid + i * 512;
        int r = e >> 3, c = (e & 7) * 8;
        *(short8*)&PbB[r * 72 + c] = *(const short8*)&q[(bh + q0 + r) * HD + c];
    }
    __syncthreads();

    const float nmask = sred[0] + sred[1] + sred[2] + sred[3] +
                        sred[4] + sred[5] + sred[6] + sred[7];

    // Q as B-operand frags for this wave's 32 queries (2 x 16)
    short8 bq_[2][2];
    for (int mi = 0; mi < 2; ++mi) {
        bq_[mi][0] = *(const short8*)&PbB[(qoff + mi * 16 + lr) * 72 + lg * 8];
        bq_[mi][1] = *(const short8*)&PbB[(qoff + mi * 16 + lr) * 72 + 32 + lg * 8];
    }

    short8 ones;
    for (int j = 0; j < 8; ++j) ones[j] = (short)0x3F80;   // bf16 1.0

    f32x4 o[2][4], lacc[2];
    for (int mi = 0; mi < 2; ++mi) {
        lacc[mi] = (f32x4){0.f,0.f,0.f,0.f};
        for (int db = 0; db < 4; ++db) o[mi][db] = (f32x4){0.f,0.f,0.f,0.f};
    }

    // staging: 512 threads x 2 chunks cover both groups' K and V tiles
    short8 pk_[2], pv_[2];
    auto ld = [&](int it) {
        int k0 = it * 64;
        for (int i = 0; i < 2; ++i) {
            int e = tid + i * 512;
            int gg = e >> 9, r = (e >> 3) & 63, c = (e & 7) * 8;
            int kk = k0 + gg * 1024;
            pk_[i] = *(const short8*)&k [(bh + kk + r) * HD + c];
            pv_[i] = *(const short8*)&vt[(bhd + r) * SEQ + kk + c];
        }
    };
    ld(0);

    for (int it = 0; it < 16; ++it) {
        for (int i = 0; i < 2; ++i) {
            int e = tid + i * 512;
            int gg = e >> 9, r = (e >> 3) & 63, c = (e & 7) * 8;
            *(short8*)&KsB[(gg * 64 + r) * 72 + c] = pk_[i];
            *(short8*)&VtB[(gg * 64 + r) * 72 + c] = pv_[i];
        }
        __syncthreads();
        if (it + 1 < 16) ld(it + 1);

        // S^T = K Q^T over this group's 64-key tile
        for (int cb = 0; cb < 4; ++cb) {
            short8 a0 = *(const short8*)&KsB[(g * 64 + cb * 16 + lr) * 72 + lg * 8];
            short8 a1 = *(const short8*)&KsB[(g * 64 + cb * 16 + lr) * 72 + 32 + lg * 8];
            for (int mi = 0; mi < 2; ++mi) {
                f32x4 cc = (f32x4){0.f,0.f,0.f,0.f};
                cc = __builtin_amdgcn_mfma_f32_16x16x32_bf16(a0, bq_[mi][0], cc, 0, 0, 0);
                cc = __builtin_amdgcn_mfma_f32_16x16x32_bf16(a1, bq_[mi][1], cc, 0, 0, 0);
                uint2v pkv = {
                    cvt_pk_bf16(__builtin_amdgcn_exp2f(cc[0]),
                                __builtin_amdgcn_exp2f(cc[1])),
                    cvt_pk_bf16(__builtin_amdgcn_exp2f(cc[2]),
                                __builtin_amdgcn_exp2f(cc[3])) };
                *(uint2v*)&PbB[(g * 128 + qoff + mi * 16 + lr) * 72 + cb * 16 + lg * 4] = pkv;
            }
        }

        // O += P V ; l += P 1   (wave-private P rows: no barrier needed)
        short8 ap[2][2];
        for (int mi = 0; mi < 2; ++mi) {
            ap[mi][0] = *(const short8*)&PbB[(g * 128 + qoff + mi * 16 + lr) * 72 + lg * 8];
            ap[mi][1] = *(const short8*)&PbB[(g * 128 + qoff + mi * 16 + lr) * 72 + 32 + lg * 8];
        }
        for (int db = 0; db < 4; ++db) {
            short8 bv0 = *(const short8*)&VtB[(g * 64 + db * 16 + lr) * 72 + lg * 8];
            short8 bv1 = *(const short8*)&VtB[(g * 64 + db * 16 + lr) * 72 + 32 + lg * 8];
            for (int mi = 0; mi < 2; ++mi) {
                o[mi][db] = __builtin_amdgcn_mfma_f32_16x16x32_bf16(ap[mi][0], bv0, o[mi][db], 0, 0, 0);
                o[mi][db] = __builtin_amdgcn_mfma_f32_16x16x32_bf16(ap[mi][1], bv1, o[mi][db], 0, 0, 0);
            }
        }
        for (int mi = 0; mi < 2; ++mi) {
            lacc[mi] = __builtin_amdgcn_mfma_f32_16x16x32_bf16(ap[mi][0], ones, lacc[mi], 0, 0, 0);
            lacc[mi] = __builtin_amdgcn_mfma_f32_16x16x32_bf16(ap[mi][1], ones, lacc[mi], 0, 0, 0);
        }
        __syncthreads();
    }

    // combine the two key-halves through LDS scratch, normalize, store
    float* Osc  = (float*)(smem + 36864);  // 32 KB over Ks+Vt
    float* larr = (float*)smem;            // over Pb[0]
    if (g == 1) {
        for (int mi = 0; mi < 2; ++mi) {
            for (int db = 0; db < 4; ++db)
                for (int r = 0; r < 4; ++r)
                    Osc[(qoff + mi * 16 + lg * 4 + r) * 64 + db * 16 + lr] = o[mi][db][r];
            if (lr == 0)
                for (int r = 0; r < 4; ++r)
                    larr[qoff + mi * 16 + lg * 4 + r] = lacc[mi][r];
        }
    }
    __syncthreads();
    if (g == 0) {
        for (int mi = 0; mi < 2; ++mi) {
            int qr = qoff + mi * 16 + lg * 4;
            f32x4 linv;
            for (int r = 0; r < 4; ++r)
                linv[r] = 1.f / (lacc[mi][r] + larr[qr + r] - nmask);
            for (int db = 0; db < 4; ++db) {
                int col = h * HD + db * 16 + lr;
                float vv[4];
                for (int r = 0; r < 4; ++r)
                    vv[r] = (o[mi][db][r] + Osc[(qr + r) * 64 + db * 16 + lr]) * linv[r];
                bf16* p = attn + ((size_t)b * SEQ + q0 + qr) * EMB + col;
                st_bf2(p,           p + EMB,     vv[0], vv[1]);
                st_bf2(p + 2 * EMB, p + 3 * EMB, vv[2], vv[3]);
            }
        }
    }
}

// ---------------------------------------------------------------------------
extern "C" void kernel_launch(void* const* d_in, const int* in_sizes, int n_in,
                              void* d_out, int out_size, void* d_ws, size_t ws_size,
                              hipStream_t stream)
{
    const float* x    = (const float*)d_in[0];
    const int*   mask = (const int*)d_in[1];
    const float* Wq   = (const float*)d_in[2];
    const float* bq   = (const float*)d_in[3];
    const float* Wk   = (const float*)d_in[4];
    const float* bk   = (const float*)d_in[5];
    const float* Wv   = (const float*)d_in[6];
    const float* bv   = (const float*)d_in[7];
    const float* Wo   = (const float*)d_in[8];
    const float* bo   = (const float*)d_in[9];
    float* out = (float*)d_out;

    const size_t TENS = (size_t)BATCH * SEQ * EMB;   // 2^22
    bf16* q    = (bf16*)d_ws;
    bf16* kt   = q    + TENS;
    bf16* vt   = kt   + TENS;
    bf16* attn = vt   + TENS;
    bf16* xb   = attn + TENS;
    bf16* wb   = xb   + TENS;     // 4 x 2^20 = TENS

    cvt_pack<<<8192, 256, 0, stream>>>(x, Wq, Wk, Wv, Wo, (short*)xb);

    gemm_qkv2<<<768, 256, 0, stream>>>(xb, wb, bq, bk, bv, mask, q, kt, vt);

    attn_flash11<<<dim3(SEQ / 128, NH, BATCH), 512, 0, stream>>>(q, kt, vt, mask, attn);

    gemm_out5<<<1024, 128, 0, stream>>>(attn, wb + ((size_t)3 << 20), bo, out);
}

// Round 12
// 190.775 us; speedup vs baseline: 1.0427x; 1.0051x over previous
//
#include <hip/hip_runtime.h>
#include <hip/hip_bf16.h>
#include <math.h>

#define BATCH 2
#define SEQ   2048
#define EMB   1024
#define NH    16
#define HD    64
#define K_DIM 1024
#define QSCALE 0.18033688011f   /* 0.125 * log2(e): folded into q projection */

typedef __hip_bfloat16 bf16;
typedef __attribute__((ext_vector_type(8))) short short8;
typedef __attribute__((ext_vector_type(4))) short short4v;
typedef __attribute__((ext_vector_type(4))) float f32x4;
typedef __attribute__((ext_vector_type(2))) unsigned int uint2v;

// gfx950 HW packed f32->bf16 (RTNE)
__device__ __forceinline__ unsigned cvt_pk_bf16(float a, float b) {
    unsigned r;
    asm("v_cvt_pk_bf16_f32 %0, %1, %2" : "=v"(r) : "v"(a), "v"(b));
    return r;
}
__device__ __forceinline__ void st_bf2(bf16* p0, bf16* p1, float a, float b) {
    unsigned pk = cvt_pk_bf16(a, b);
    *(short*)p0 = (short)(pk & 0xffff);
    *(short*)p1 = (short)(pk >> 16);
}

// async global->LDS, 16B per lane; LDS dest = wave-uniform base + lane*16
__device__ __forceinline__ void gld_lds16(const bf16* g, bf16* l) {
    __builtin_amdgcn_global_load_lds(
        (const __attribute__((address_space(1))) unsigned int*)g,
        (__attribute__((address_space(3))) unsigned int*)l, 16, 0, 0);
}

// ---------------------------------------------------------------------------
// Convert x and Wq|Wk|Wv|Wo to bf16 into contiguous dst [xb | wq wk wv wo].
// At its 72MB HBM roofline (~8us).
// ---------------------------------------------------------------------------
__global__ __launch_bounds__(256)
void cvt_pack(const float* __restrict__ x,  const float* __restrict__ wq,
              const float* __restrict__ wk, const float* __restrict__ wv,
              const float* __restrict__ wo, short* __restrict__ dst)
{
    size_t gid = ((size_t)blockIdx.x * 256 + threadIdx.x) * 4;
    int seg = (int)(gid >> 20);
    const float* src; size_t off;
    if (seg < 4)       { src = x;  off = gid; }
    else if (seg == 4) { src = wq; off = gid - ((size_t)4 << 20); }
    else if (seg == 5) { src = wk; off = gid - ((size_t)5 << 20); }
    else if (seg == 6) { src = wv; off = gid - ((size_t)6 << 20); }
    else               { src = wo; off = gid - ((size_t)7 << 20); }
    f32x4 v = *(const f32x4*)(src + off);
    uint2v pk = { cvt_pk_bf16(v[0], v[1]), cvt_pk_bf16(v[2], v[3]) };
    *(uint2v*)(dst + gid) = pk;
}

// ---------------------------------------------------------------------------
// Fused QKV GEMM (round-0 verified form, best-measured config). 635 TF for
// M=4096/N=1024 panels -- above the m97-structure shape curve; structural
// A/Bs across R7-R11 (retile epilogue, BK=64+swizzle, XCD relabel) were all
// null-to-negative. At its 2-barrier-structure floor.
// ---------------------------------------------------------------------------
__global__ __launch_bounds__(256)
void gemm_qkv2(const bf16* __restrict__ xb, const bf16* __restrict__ wb,
               const float* __restrict__ bq, const float* __restrict__ bk_,
               const float* __restrict__ bv_, const int* __restrict__ mask,
               bf16* __restrict__ q, bf16* __restrict__ kt, bf16* __restrict__ vt)
{
    __shared__ __align__(16) bf16 As[128 * 32];
    __shared__ __align__(16) bf16 Bs[128 * 32];

    const int tid  = threadIdx.x;
    const int proj = blockIdx.x >> 3;
    const int n0   = (blockIdx.x & 7) * 128;
    const int m0   = blockIdx.y * 128;
    const bf16* W  = wb + ((size_t)proj << 20);
    const float* bias = (proj == 0) ? bq : (proj == 1) ? bk_ : bv_;

    const int wave = tid >> 6, lane = tid & 63;
    const int wm = wave >> 1, wn = wave & 1;
    const int lr = lane & 15, lg = lane >> 4;
    const int srow = lane >> 2;
    const int scol = (lane & 3) * 8;

    f32x4 acc[4][4];
    for (int mi = 0; mi < 4; ++mi)
        for (int ni = 0; ni < 4; ++ni) acc[mi][ni] = (f32x4){0.f,0.f,0.f,0.f};

    for (int k0 = 0; k0 < K_DIM; k0 += 32) {
        for (int i = 0; i < 2; ++i) {
            int rb = (wave * 2 + i) * 16;
            gld_lds16(&xb[(size_t)(m0 + rb + srow) * K_DIM + k0 + scol], &As[rb * 32]);
            gld_lds16(&W [(size_t)(n0 + rb + srow) * K_DIM + k0 + scol], &Bs[rb * 32]);
        }
        __syncthreads();
        short8 af[4], bf_[4];
        for (int mi = 0; mi < 4; ++mi)
            af[mi]  = *(const short8*)&As[(wm * 64 + mi * 16 + lr) * 32 + lg * 8];
        for (int ni = 0; ni < 4; ++ni)
            bf_[ni] = *(const short8*)&Bs[(wn * 64 + ni * 16 + lr) * 32 + lg * 8];
        for (int mi = 0; mi < 4; ++mi)
            for (int ni = 0; ni < 4; ++ni)
                acc[mi][ni] = __builtin_amdgcn_mfma_f32_16x16x32_bf16(
                    af[mi], bf_[ni], acc[mi][ni], 0, 0, 0);
        __syncthreads();
    }

    int msk[4][4];
    if (proj != 0) {
        for (int mi = 0; mi < 4; ++mi) {
            int mbase = m0 + wm * 64 + mi * 16 + lg * 4;
            int b = mbase >> 11, s0 = mbase & 2047;
            int4 mm = *(const int4*)&mask[(size_t)b * SEQ + s0];
            msk[mi][0] = mm.x; msk[mi][1] = mm.y; msk[mi][2] = mm.z; msk[mi][3] = mm.w;
        }
    }

    for (int mi = 0; mi < 4; ++mi)
        for (int ni = 0; ni < 4; ++ni) {
            int n = n0 + wn * 64 + ni * 16 + lr;
            float bvv = bias[n];
            int h = n >> 6, d = n & 63;
            int mbase = m0 + wm * 64 + mi * 16 + lg * 4;
            int b = mbase >> 11, s0 = mbase & 2047;
            float v0 = acc[mi][ni][0] + bvv, v1 = acc[mi][ni][1] + bvv;
            float v2 = acc[mi][ni][2] + bvv, v3 = acc[mi][ni][3] + bvv;
            if (proj == 0) {
                bf16* p = q + ((((size_t)b * NH) + h) * SEQ + s0) * HD + d;
                st_bf2(p,          p + HD,     v0 * QSCALE, v1 * QSCALE);
                st_bf2(p + 2 * HD, p + 3 * HD, v2 * QSCALE, v3 * QSCALE);
            } else if (proj == 1) {
                if (msk[mi][0]) v0 = 0.f;
                if (msk[mi][1]) v1 = 0.f;
                if (msk[mi][2]) v2 = 0.f;
                if (msk[mi][3]) v3 = 0.f;
                bf16* p = kt + ((((size_t)b * NH) + h) * SEQ + s0) * HD + d;
                st_bf2(p,          p + HD,     v0, v1);
                st_bf2(p + 2 * HD, p + 3 * HD, v2, v3);
            } else {
                if (msk[mi][0]) v0 = 0.f;
                if (msk[mi][1]) v1 = 0.f;
                if (msk[mi][2]) v2 = 0.f;
                if (msk[mi][3]) v3 = 0.f;
                uint2v pk = { cvt_pk_bf16(v0, v1), cvt_pk_bf16(v2, v3) };
                *(uint2v*)((short*)vt + ((((size_t)b * NH) + h) * HD + d) * SEQ + s0) = pk;
            }
        }
}

// ---------------------------------------------------------------------------
// Out projection (round-0 verified form). Structure A/Bs (128x128 8-wave,
// BK=64+swizzle, 64x64 4-blocks/CU, XCD relabels) all landed within noise.
// ---------------------------------------------------------------------------
__global__ __launch_bounds__(256)
void gemm_out2(const bf16* __restrict__ A, const bf16* __restrict__ W,
               const float* __restrict__ bias, float* __restrict__ C)
{
    __shared__ __align__(16) bf16 As[128 * 32];
    __shared__ __align__(16) bf16 Bs[64 * 32];

    const int tid = threadIdx.x;
    const int n0  = blockIdx.x * 64;
    const int m0  = blockIdx.y * 128;
    const int wave = tid >> 6, lane = tid & 63;
    const int wm = wave >> 1, wn = wave & 1;
    const int lr = lane & 15, lg = lane >> 4;
    const int srow = lane >> 2, scol = (lane & 3) * 8;

    f32x4 acc[4][2];
    for (int mi = 0; mi < 4; ++mi)
        for (int ni = 0; ni < 2; ++ni) acc[mi][ni] = (f32x4){0.f,0.f,0.f,0.f};

    for (int k0 = 0; k0 < K_DIM; k0 += 32) {
        for (int i = 0; i < 2; ++i) {
            int rb = (wave * 2 + i) * 16;
            gld_lds16(&A[(size_t)(m0 + rb + srow) * K_DIM + k0 + scol], &As[rb * 32]);
        }
        {
            int rb = wave * 16;
            gld_lds16(&W[(size_t)(n0 + rb + srow) * K_DIM + k0 + scol], &Bs[rb * 32]);
        }
        __syncthreads();
        short8 af[4], bf_[2];
        for (int mi = 0; mi < 4; ++mi)
            af[mi]  = *(const short8*)&As[(wm * 64 + mi * 16 + lr) * 32 + lg * 8];
        for (int ni = 0; ni < 2; ++ni)
            bf_[ni] = *(const short8*)&Bs[(wn * 32 + ni * 16 + lr) * 32 + lg * 8];
        for (int mi = 0; mi < 4; ++mi)
            for (int ni = 0; ni < 2; ++ni)
                acc[mi][ni] = __builtin_amdgcn_mfma_f32_16x16x32_bf16(
                    af[mi], bf_[ni], acc[mi][ni], 0, 0, 0);
        __syncthreads();
    }

    for (int mi = 0; mi < 4; ++mi)
        for (int ni = 0; ni < 2; ++ni) {
            int n = n0 + wn * 32 + ni * 16 + lr;
            float bvv = bias[n];
            int mbase = m0 + wm * 64 + mi * 16 + lg * 4;
            for (int r = 0; r < 4; ++r)
                C[(size_t)(mbase + r) * EMB + n] = acc[mi][ni][r] + bvv;
        }
}

// ---------------------------------------------------------------------------
// Flash attention v11 (best-measured green, 49.7us = 702 TF): round-0
// attn_flash6 + XCD swizzle (FETCH 69.7->12.4MB, K/V L2-resident).
// Structure-bound, not memory-bound; in-loop edits (v7/v8/v10) all corrupt.
// FROZEN at 78% of the m214 plain-HIP reference rate.
// ---------------------------------------------------------------------------
__global__ __launch_bounds__(512, 4)
void attn_flash11(const bf16* __restrict__ q, const bf16* __restrict__ k,
                  const bf16* __restrict__ vt, const int* __restrict__ mask,
                  bf16* __restrict__ attn)
{
    __shared__ __align__(16) char smem[73728];
    bf16* PbB = (bf16*)smem;              // [2][128][72]  (g0 doubles as Q stage)
    bf16* KsB = (bf16*)(smem + 36864);    // [2][64][72]
    bf16* VtB = (bf16*)(smem + 55296);    // [2][64][72]
    __shared__ float sred[8];

    // XCD-aware bijective relabeling of (q0, h, b); grid = dim3(16,16,2).
    const int bid = (int)blockIdx.x + ((int)blockIdx.y << 4) + ((int)blockIdx.z << 8);
    const int swz = (bid & 7) * 64 + (bid >> 3);
    const int q0  = (swz & 15) * 128;
    const int h   = (swz >> 4) & 15;
    const int b   = swz >> 8;

    const int tid  = threadIdx.x;
    const int lane = tid & 63;
    const int wave = tid >> 6;            // 0..7
    const int g    = wave >> 2;           // key group 0/1
    const int qoff = (wave & 3) * 32;     // this wave's 32 query rows
    const int lr   = lane & 15;
    const int lg   = lane >> 4;

    const size_t bh  = ((size_t)b * NH + h) * SEQ;
    const size_t bhd = ((size_t)b * NH + h) * HD;

    // masked-key count for batch b
    int4 mm = *(const int4*)&mask[(size_t)b * SEQ + tid * 4];
    int cnt = (mm.x != 0) + (mm.y != 0) + (mm.z != 0) + (mm.w != 0);
    for (int off = 32; off; off >>= 1) cnt += __shfl_xor(cnt, off);
    if (lane == 0) sred[wave] = (float)cnt;

    // stage Q tile into Pb[0] region (8192 elems, 16/thread)
    for (int i = 0; i < 2; ++i) {
        int e = tid + i * 512;
        int r = e >> 3, c = (e & 7) * 8;
        *(short8*)&PbB[r * 72 + c] = *(const short8*)&q[(bh + q0 + r) * HD + c];
    }
    __syncthreads();

    const float nmask = sred[0] + sred[1] + sred[2] + sred[3] +
                        sred[4] + sred[5] + sred[6] + sred[7];

    // Q as B-operand frags for this wave's 32 queries (2 x 16)
    short8 bq_[2][2];
    for (int mi = 0; mi < 2; ++mi) {
        bq_[mi][0] = *(const short8*)&PbB[(qoff + mi * 16 + lr) * 72 + lg * 8];
        bq_[mi][1] = *(const short8*)&PbB[(qoff + mi * 16 + lr) * 72 + 32 + lg * 8];
    }

    short8 ones;
    for (int j = 0; j < 8; ++j) ones[j] = (short)0x3F80;   // bf16 1.0

    f32x4 o[2][4], lacc[2];
    for (int mi = 0; mi < 2; ++mi) {
        lacc[mi] = (f32x4){0.f,0.f,0.f,0.f};
        for (int db = 0; db < 4; ++db) o[mi][db] = (f32x4){0.f,0.f,0.f,0.f};
    }

    // staging: 512 threads x 2 chunks cover both groups' K and V tiles
    short8 pk_[2], pv_[2];
    auto ld = [&](int it) {
        int k0 = it * 64;
        for (int i = 0; i < 2; ++i) {
            int e = tid + i * 512;
            int gg = e >> 9, r = (e >> 3) & 63, c = (e & 7) * 8;
            int kk = k0 + gg * 1024;
            pk_[i] = *(const short8*)&k [(bh + kk + r) * HD + c];
            pv_[i] = *(const short8*)&vt[(bhd + r) * SEQ + kk + c];
        }
    };
    ld(0);

    for (int it = 0; it < 16; ++it) {
        for (int i = 0; i < 2; ++i) {
            int e = tid + i * 512;
            int gg = e >> 9, r = (e >> 3) & 63, c = (e & 7) * 8;
            *(short8*)&KsB[(gg * 64 + r) * 72 + c] = pk_[i];
            *(short8*)&VtB[(gg * 64 + r) * 72 + c] = pv_[i];
        }
        __syncthreads();
        if (it + 1 < 16) ld(it + 1);

        // S^T = K Q^T over this group's 64-key tile
        for (int cb = 0; cb < 4; ++cb) {
            short8 a0 = *(const short8*)&KsB[(g * 64 + cb * 16 + lr) * 72 + lg * 8];
            short8 a1 = *(const short8*)&KsB[(g * 64 + cb * 16 + lr) * 72 + 32 + lg * 8];
            for (int mi = 0; mi < 2; ++mi) {
                f32x4 cc = (f32x4){0.f,0.f,0.f,0.f};
                cc = __builtin_amdgcn_mfma_f32_16x16x32_bf16(a0, bq_[mi][0], cc, 0, 0, 0);
                cc = __builtin_amdgcn_mfma_f32_16x16x32_bf16(a1, bq_[mi][1], cc, 0, 0, 0);
                uint2v pkv = {
                    cvt_pk_bf16(__builtin_amdgcn_exp2f(cc[0]),
                                __builtin_amdgcn_exp2f(cc[1])),
                    cvt_pk_bf16(__builtin_amdgcn_exp2f(cc[2]),
                                __builtin_amdgcn_exp2f(cc[3])) };
                *(uint2v*)&PbB[(g * 128 + qoff + mi * 16 + lr) * 72 + cb * 16 + lg * 4] = pkv;
            }
        }

        // O += P V ; l += P 1   (wave-private P rows: no barrier needed)
        short8 ap[2][2];
        for (int mi = 0; mi < 2; ++mi) {
            ap[mi][0] = *(const short8*)&PbB[(g * 128 + qoff + mi * 16 + lr) * 72 + lg * 8];
            ap[mi][1] = *(const short8*)&PbB[(g * 128 + qoff + mi * 16 + lr) * 72 + 32 + lg * 8];
        }
        for (int db = 0; db < 4; ++db) {
            short8 bv0 = *(const short8*)&VtB[(g * 64 + db * 16 + lr) * 72 + lg * 8];
            short8 bv1 = *(const short8*)&VtB[(g * 64 + db * 16 + lr) * 72 + 32 + lg * 8];
            for (int mi = 0; mi < 2; ++mi) {
                o[mi][db] = __builtin_amdgcn_mfma_f32_16x16x32_bf16(ap[mi][0], bv0, o[mi][db], 0, 0, 0);
                o[mi][db] = __builtin_amdgcn_mfma_f32_16x16x32_bf16(ap[mi][1], bv1, o[mi][db], 0, 0, 0);
            }
        }
        for (int mi = 0; mi < 2; ++mi) {
            lacc[mi] = __builtin_amdgcn_mfma_f32_16x16x32_bf16(ap[mi][0], ones, lacc[mi], 0, 0, 0);
            lacc[mi] = __builtin_amdgcn_mfma_f32_16x16x32_bf16(ap[mi][1], ones, lacc[mi], 0, 0, 0);
        }
        __syncthreads();
    }

    // combine the two key-halves through LDS scratch, normalize, store
    float* Osc  = (float*)(smem + 36864);  // 32 KB over Ks+Vt
    float* larr = (float*)smem;            // over Pb[0]
    if (g == 1) {
        for (int mi = 0; mi < 2; ++mi) {
            for (int db = 0; db < 4; ++db)
                for (int r = 0; r < 4; ++r)
                    Osc[(qoff + mi * 16 + lg * 4 + r) * 64 + db * 16 + lr] = o[mi][db][r];
            if (lr == 0)
                for (int r = 0; r < 4; ++r)
                    larr[qoff + mi * 16 + lg * 4 + r] = lacc[mi][r];
        }
    }
    __syncthreads();
    if (g == 0) {
        for (int mi = 0; mi < 2; ++mi) {
            int qr = qoff + mi * 16 + lg * 4;
            f32x4 linv;
            for (int r = 0; r < 4; ++r)
                linv[r] = 1.f / (lacc[mi][r] + larr[qr + r] - nmask);
            for (int db = 0; db < 4; ++db) {
                int col = h * HD + db * 16 + lr;
                float vv[4];
                for (int r = 0; r < 4; ++r)
                    vv[r] = (o[mi][db][r] + Osc[(qr + r) * 64 + db * 16 + lr]) * linv[r];
                bf16* p = attn + ((size_t)b * SEQ + q0 + qr) * EMB + col;
                st_bf2(p,           p + EMB,     vv[0], vv[1]);
                st_bf2(p + 2 * EMB, p + 3 * EMB, vv[2], vv[3]);
            }
        }
    }
}

// ---------------------------------------------------------------------------
extern "C" void kernel_launch(void* const* d_in, const int* in_sizes, int n_in,
                              void* d_out, int out_size, void* d_ws, size_t ws_size,
                              hipStream_t stream)
{
    const float* x    = (const float*)d_in[0];
    const int*   mask = (const int*)d_in[1];
    const float* Wq   = (const float*)d_in[2];
    const float* bq   = (const float*)d_in[3];
    const float* Wk   = (const float*)d_in[4];
    const float* bk   = (const float*)d_in[5];
    const float* Wv   = (const float*)d_in[6];
    const float* bv   = (const float*)d_in[7];
    const float* Wo   = (const float*)d_in[8];
    const float* bo   = (const float*)d_in[9];
    float* out = (float*)d_out;

    const size_t TENS = (size_t)BATCH * SEQ * EMB;   // 2^22
    bf16* q    = (bf16*)d_ws;
    bf16* kt   = q    + TENS;
    bf16* vt   = kt   + TENS;
    bf16* attn = vt   + TENS;
    bf16* xb   = attn + TENS;
    bf16* wb   = xb   + TENS;     // 4 x 2^20 = TENS

    cvt_pack<<<8192, 256, 0, stream>>>(x, Wq, Wk, Wv, Wo, (short*)xb);

    gemm_qkv2<<<dim3(24, 32), 256, 0, stream>>>(xb, wb, bq, bk, bv, mask, q, kt, vt);

    attn_flash11<<<dim3(SEQ / 128, NH, BATCH), 512, 0, stream>>>(q, kt, vt, mask, attn);

    gemm_out2<<<dim3(16, 32), 256, 0, stream>>>(attn, wb + ((size_t)3 << 20), bo, out);
}